// Round 7
// baseline (486.879 us; speedup 1.0000x reference)
//
#include <hip/hip_runtime.h>
#include <cstdint>
#include <cstddef>

typedef unsigned int u32;
typedef unsigned short u16;
typedef __bf16 bf16x8 __attribute__((ext_vector_type(8)));
typedef float f32x4 __attribute__((ext_vector_type(4)));
typedef u16 u16x8 __attribute__((ext_vector_type(8)));

static constexpr int T_TOK = 4096;
static constexpr int HID   = 2048;
static constexpr int INTER = 1024;
static constexpr int NEXP  = 8;
static constexpr int TOPK  = 2;
static constexpr int SLOT_CAP = 10240;   // 8192 real + per-expert 256-align pad
static constexpr int NT_M = 40;

// meta int indices
static constexpr int M_TOT  = 16;
static constexpr int M_CUR  = 17;   // 8 router cursors
static constexpr int M_Q    = 25;   // queue cursor
static constexpr int M_CAST = 26;
static constexpr int M_ZERO = 27;
static constexpr int M_W2   = 28;
static constexpr int M_W1   = 29;   // 8 per-expert
static constexpr int M_DONE = 40;   // 40 per-mt
static constexpr int M_TOK  = 96;   // toklist[SLOT_CAP]
static constexpr int M_INTS = 96 + SLOT_CAP;  // then ewslot[SLOT_CAP] floats

// work queue layout
static constexpr int N_CAST = 32, N_ZERO = 32, N_W2 = 64, N_W1 = 128, N_G = 320;
static constexpr int IT_ZERO0 = 32, IT_W20 = 64, IT_W10 = 128, IT_G10 = 256,
                     IT_G20 = 576, N_ITEMS = 896;

__device__ __forceinline__ u16 f2bf(float f) {
  u32 u = __builtin_bit_cast(u32, f);
  u32 r = (u + 0x7fffu + ((u >> 16) & 1u)) >> 16;
  return (u16)r;
}
__device__ __forceinline__ float bf2f(u16 h) {
  return __builtin_bit_cast(float, (u32)h << 16);
}

__device__ __forceinline__ void spin_ge(int* p, int target) {
  while (__hip_atomic_load(p, __ATOMIC_ACQUIRE, __HIP_MEMORY_SCOPE_AGENT) < target)
    __builtin_amdgcn_s_sleep(8);
}
// call pattern: all stores done -> __syncthreads() (drains vmcnt of all waves)
// -> tid0: __threadfence() (L2 writeback) + release add.
__device__ __forceinline__ void bump(int* p, int tid) {
  __syncthreads();
  if (tid == 0) {
    __threadfence();
    __hip_atomic_fetch_add(p, 1, __ATOMIC_RELEASE, __HIP_MEMORY_SCOPE_AGENT);
  }
}

// ---------------- router ----------------
__global__ void router_count(const int* __restrict__ eidx, int* __restrict__ meta) {
  __shared__ int cnt[NEXP];
  const int tid = threadIdx.x;
  if (tid < NEXP) cnt[tid] = 0;
  __syncthreads();
  for (int i = tid; i < T_TOK * TOPK; i += 256) atomicAdd(&cnt[eidx[i]], 1);
  __syncthreads();
  if (tid == 0) {
    int off = 0;
    for (int e = 0; e < NEXP; ++e) {
      int c = cnt[e];
      meta[e] = c;
      meta[8 + e] = off;
      meta[M_CUR + e] = off;
      off += (c + 255) & ~255;      // 256-aligned regions (BM=256)
    }
    meta[M_TOT] = off;
  }
}

__global__ void init_k(int* __restrict__ meta) {
  const int i = blockIdx.x * 256 + threadIdx.x;
  float* ewslot = (float*)(meta + M_INTS);
  if (i < SLOT_CAP) {
    meta[M_TOK + i] = 0;   // pad rows gather token 0
    ewslot[i] = 0.0f;      // pad rows contribute weight 0
  }
  if (blockIdx.x == 0 && threadIdx.x < 71) meta[M_Q + threadIdx.x] = 0;
}

__global__ void router_assign(const int* __restrict__ eidx, const float* __restrict__ ew,
                              int* __restrict__ meta) {
  const int t = blockIdx.x * 256 + threadIdx.x;
  if (t >= T_TOK) return;
  int* cursors = meta + M_CUR;
  int* toklist = meta + M_TOK;
  float* ewslot = (float*)(meta + M_INTS);
  for (int k = 0; k < TOPK; ++k) {
    const int e = eidx[t * TOPK + k];
    const int pos = atomicAdd(&cursors[e], 1);
    toklist[pos] = t;
    ewslot[pos] = ew[t * TOPK + k];
  }
}

// ---------------- dequant helper (1 thread = 4 int32 -> 8 bf16) ----------------
template <int CPR>
__device__ __forceinline__ void deq1(const int* __restrict__ p, const float* __restrict__ s,
                                     u16* __restrict__ w, int gid) {
  const int row = gid / CPR;
  const int cid = gid % CPR;
  const int4 pk = *(const int4*)(p + (size_t)gid * 4);
  const float sc = s[(size_t)row * (CPR / 4) + (cid >> 2)];
  int v[4] = {pk.x, pk.y, pk.z, pk.w};
  u16x8 o;
#pragma unroll
  for (int b = 0; b < 4; ++b) {
    o[2 * b]     = f2bf((float)((v[b] & 15) - 8) * sc);
    o[2 * b + 1] = f2bf((float)(((v[b] >> 4) & 15) - 8) * sc);
  }
  *(u16x8*)(w + (size_t)gid * 8) = o;
}

// ---------------- 256x256 GEMM tile body (8-phase, counted vmcnt) ----------------
// Swizzle fix vs R6: conflict-free requires chunk c' = c ^ ((row>>1)&3)
// (bank-quads {0,4,1,5,2,6,3,7} per 8-lane service group -> bijection);
// R6's ((row>>2)&3) was 2-way aliased. Byte form: o ^= ((o>>7)&3)<<4.
template <int KT, bool GUP>
__device__ void gemm_body(const u16* __restrict__ A, const u16* __restrict__ Be,
                          u16* __restrict__ hb, float* __restrict__ out,
                          const int* __restrict__ toklist, const float* __restrict__ ewslot,
                          u16* lds, int slot0, int nt, int tid) {
  static constexpr int NT = KT / 64;
  static constexpr int OSTR = GUP ? INTER : HID;
  char* ldsB = (char*)lds;

  const u16* asrc[4];
  const u16* bsrc[4];
#pragma unroll
  for (int j = 0; j < 4; ++j) {
    const int L = j * 8192 + tid * 16;
    const int S = L >> 10;
    int o = L & 1023;
    o ^= ((o >> 7) & 3) << 4;
    const int r = (S >> 1) * 16 + (o >> 6);
    const int cb = (S & 1) * 64 + (o & 63);
    const int arow = GUP ? toklist[slot0 + r] : (slot0 + r);
    asrc[j] = A + (size_t)arow * KT + (cb >> 1);
    int brow;
    if (GUP) {
      const int g = r >> 6, j6 = r & 63;
      brow = nt * 128 + g * 32 + (j6 & 31) + ((j6 >> 5) << 10);  // gate | up+1024
    } else {
      brow = nt * 256 + r;
    }
    bsrc[j] = Be + (size_t)brow * KT + (cb >> 1);
  }

#define STG_A(kt_, c_, j_)                                                          \
  __builtin_amdgcn_global_load_lds(                                                 \
      (const __attribute__((address_space(1))) void*)(asrc[j_] + (kt_) * 64),       \
      (__attribute__((address_space(3))) void*)(ldsB + (c_) * 65536 + (j_) * 8192 + \
                                                tid * 16),                           \
      16, 0, 0)
#define STG_B(kt_, c_, j_)                                                          \
  __builtin_amdgcn_global_load_lds(                                                 \
      (const __attribute__((address_space(1))) void*)(bsrc[j_] + (kt_) * 64),       \
      (__attribute__((address_space(3))) void*)(ldsB + (c_) * 65536 + 32768 +       \
                                                (j_) * 8192 + tid * 16),             \
      16, 0, 0)

  const int lane = tid & 63;
  const int wid = tid >> 6;
  const int wm = (wid >> 2) * 128;
  const int wn = (wid & 3) * 64;
  const int fr = lane & 15;
  const int qq = lane >> 4;
  const int swz = (qq * 16) ^ (((fr >> 1) & 3) << 4);

  const int abase = (wm >> 4) * 2048 + fr * 64 + swz;
  const int bbase = 32768 + (wn >> 4) * 2048 + fr * 64 + swz;

  f32x4 acc[8][4];
#pragma unroll
  for (int m = 0; m < 8; ++m)
#pragma unroll
    for (int n = 0; n < 4; ++n) acc[m][n] = (f32x4)0.0f;

  bf16x8 af[4][2], b01[2][2], b23[2][2];

#define BARRIER asm volatile("s_barrier" ::: "memory")
#define LGKM0                                              \
  do {                                                     \
    asm volatile("s_waitcnt lgkmcnt(0)" ::: "memory");     \
    __builtin_amdgcn_sched_barrier(0);                     \
  } while (0)
#define DS_AF(c_, mh_)                                                              \
  _Pragma("unroll") for (int mf = 0; mf < 4; ++mf)                                  \
  _Pragma("unroll") for (int ks = 0; ks < 2; ++ks)                                  \
      af[mf][ks] = *(const bf16x8*)(ldsB + (c_) * 65536 + abase + (mh_) * 8192 +    \
                                    mf * 2048 + ks * 1024);
#define DS_B(c_, bh_, BV_)                                                          \
  _Pragma("unroll") for (int nf = 0; nf < 2; ++nf)                                  \
  _Pragma("unroll") for (int ks = 0; ks < 2; ++ks)                                  \
      BV_[nf][ks] = *(const bf16x8*)(ldsB + (c_) * 65536 + bbase +                  \
                                     ((bh_) * 2 + nf) * 2048 + ks * 1024);
#define MFMA16(mh_, bh_, BV_)                                                       \
  do {                                                                              \
    __builtin_amdgcn_s_setprio(1);                                                  \
    _Pragma("unroll") for (int mf = 0; mf < 4; ++mf)                                \
    _Pragma("unroll") for (int nf = 0; nf < 2; ++nf)                                \
    _Pragma("unroll") for (int ks = 0; ks < 2; ++ks)                                \
        acc[(mh_) * 4 + mf][(bh_) * 2 + nf] =                                       \
            __builtin_amdgcn_mfma_f32_16x16x32_bf16(                                \
                af[mf][ks], BV_[nf][ks], acc[(mh_) * 4 + mf][(bh_) * 2 + nf],       \
                0, 0, 0);                                                           \
    __builtin_amdgcn_s_setprio(0);                                                  \
  } while (0)

  // prologue: tiles 0 (buf0) and 1 (buf1); certify tile0 only (vmcnt in-order retire)
  STG_A(0, 0, 0); STG_A(0, 0, 2); STG_B(0, 0, 0); STG_B(0, 0, 1);
  STG_B(0, 0, 2); STG_B(0, 0, 3); STG_A(0, 0, 1); STG_A(0, 0, 3);
  STG_A(1, 1, 0); STG_A(1, 1, 2); STG_B(1, 1, 0); STG_B(1, 1, 1);
  STG_B(1, 1, 2); STG_B(1, 1, 3); STG_A(1, 1, 1); STG_A(1, 1, 3);
  asm volatile("s_waitcnt vmcnt(8)" ::: "memory");
  BARRIER;

#pragma unroll 1
  for (int it = 0; it < NT / 2; ++it) {
    const int s0 = (2 * it + 2) & (NT - 1);   // wraps at end: harmless redundant loads
    const int s1 = (2 * it + 3) & (NT - 1);
    // P1: read af0+b01(buf0); MFMA mh0 x n01
    DS_AF(0, 0); DS_B(0, 0, b01);
    BARRIER; LGKM0; MFMA16(0, 0, b01); BARRIER;
    // P2: read b23(buf0); stage s0.A02 (chunks 0,2 last read in P1); MFMA mh0 x n23
    DS_B(0, 1, b23); STG_A(s0, 0, 0); STG_A(s0, 0, 2);
    BARRIER; LGKM0; MFMA16(0, 1, b23); BARRIER;
    // P3: read af1(buf0); stage s0.B01 (B last read in P2); MFMA mh1 x n01
    DS_AF(0, 1); STG_B(s0, 0, 0); STG_B(s0, 0, 1);
    BARRIER; LGKM0; MFMA16(1, 0, b01); BARRIER;
    // P4: stage s0.B23; MFMA mh1 x n23; vmcnt(6) certifies tile(buf1)
    STG_B(s0, 0, 2); STG_B(s0, 0, 3);
    BARRIER; MFMA16(1, 1, b23);
    asm volatile("s_waitcnt vmcnt(6)" ::: "memory");
    BARRIER;
    // P5: read af0+b01(buf1); stage s0.A13 (chunks 1,3 last read in P3); MFMA mh0 x n01
    DS_AF(1, 0); DS_B(1, 0, b01); STG_A(s0, 0, 1); STG_A(s0, 0, 3);
    BARRIER; LGKM0; MFMA16(0, 0, b01); BARRIER;
    // P6: read b23(buf1); stage s1.A02; MFMA mh0 x n23
    DS_B(1, 1, b23); STG_A(s1, 1, 0); STG_A(s1, 1, 2);
    BARRIER; LGKM0; MFMA16(0, 1, b23); BARRIER;
    // P7: read af1(buf1); stage s1.B all; MFMA mh1 x n01
    DS_AF(1, 1); STG_B(s1, 1, 0); STG_B(s1, 1, 1); STG_B(s1, 1, 2); STG_B(s1, 1, 3);
    BARRIER; LGKM0; MFMA16(1, 0, b01); BARRIER;
    // P8: stage s1.A13; MFMA mh1 x n23; vmcnt(8) certifies next buf0
    STG_A(s1, 1, 1); STG_A(s1, 1, 3);
    BARRIER; MFMA16(1, 1, b23);
    asm volatile("s_waitcnt vmcnt(8)" ::: "memory");
    BARRIER;
  }
#undef STG_A
#undef STG_B
#undef BARRIER
#undef LGKM0
#undef DS_AF
#undef DS_B
#undef MFMA16

  // epilogue: C/D layout col=lane&15, row=(lane>>4)*4+j  [m89-verified]
  if (GUP) {
    const int g = wid & 3;
#pragma unroll
    for (int mi = 0; mi < 8; ++mi)
#pragma unroll
      for (int n = 0; n < 2; ++n)
#pragma unroll
        for (int jj = 0; jj < 4; ++jj) {
          const float gv = acc[mi][n][jj];
          const float uv = acc[mi][n + 2][jj];
          const float hv = gv / (1.0f + __expf(-gv)) * uv;
          const int row = slot0 + wm + mi * 16 + qq * 4 + jj;
          hb[(size_t)row * OSTR + nt * 128 + g * 32 + n * 16 + fr] = f2bf(hv);
        }
  } else {
    // scatter-combine: out[tok, col] += w * val (2 exact-commutative adds/cell)
#pragma unroll
    for (int mi = 0; mi < 8; ++mi)
#pragma unroll
      for (int jj = 0; jj < 4; ++jj) {
        const int slot = slot0 + wm + mi * 16 + qq * 4 + jj;
        const int tok = toklist[slot];
        const float w = ewslot[slot];
        float* orow = out + (size_t)tok * HID + nt * 256 + wn + fr;
#pragma unroll
        for (int n = 0; n < 4; ++n)
          atomicAdd(orow + n * 16, w * acc[mi][n][jj]);
      }
  }
}

// ---------------- persistent fused kernel (work queue, 256 blocks) ----------------
// Queue: [cast x 32][zero out 32][deq W2 64][deq W1 128 expert-major]
//        [G1 tiles 320 mt-major][G2 tiles 320 mt-major]
// Deps via release counters + acquire spins. Deadlock-free by induction: pops are
// in cursor order and every dependency is strictly earlier in the queue, so any
// spinning block's dependency is held by a block that makes progress.
__global__ __launch_bounds__(512, 2) void fused(
    const float* __restrict__ x, const int* __restrict__ w1,
    const float* __restrict__ w1s, const int* __restrict__ w2,
    const float* __restrict__ w2s, u16* __restrict__ xb, u16* __restrict__ W1b,
    u16* __restrict__ W2b, u16* __restrict__ hbuf, float* __restrict__ out,
    int* __restrict__ meta) {
  __shared__ u16 lds[2 * 32768];
  __shared__ int sh_item;
  const int tid = threadIdx.x;
  const int* toklist = meta + M_TOK;
  const float* ewslot = (const float*)(meta + M_INTS);

  for (;;) {
    __syncthreads();
    if (tid == 0) sh_item = atomicAdd(&meta[M_Q], 1);
    __syncthreads();
    const int item = sh_item;
    if (item >= N_ITEMS) return;

    if (item < IT_ZERO0) {
      // cast x -> bf16, 262144 elems
      const int base = item * 262144;
      for (int i2 = 0; i2 < 64; ++i2) {
        const int i = base + i2 * 4096 + tid * 8;
        const float4 a = *(const float4*)(x + i);
        const float4 b = *(const float4*)(x + i + 4);
        u16x8 o;
        o[0] = f2bf(a.x); o[1] = f2bf(a.y); o[2] = f2bf(a.z); o[3] = f2bf(a.w);
        o[4] = f2bf(b.x); o[5] = f2bf(b.y); o[6] = f2bf(b.z); o[7] = f2bf(b.w);
        *(u16x8*)(xb + i) = o;
      }
      bump(&meta[M_CAST], tid);
    } else if (item < IT_W20) {
      // zero out, 262144 floats
      const int base = (item - IT_ZERO0) * 262144;
      const float4 z = {0.f, 0.f, 0.f, 0.f};
      for (int i2 = 0; i2 < 128; ++i2)
        *(float4*)(out + base + i2 * 2048 + tid * 4) = z;
      bump(&meta[M_ZERO], tid);
    } else if (item < IT_W10) {
      const int g0 = (item - IT_W20) * 32768;
      for (int i2 = 0; i2 < 64; ++i2) deq1<128>(w2, w2s, W2b, g0 + i2 * 512 + tid);
      bump(&meta[M_W2], tid);
    } else if (item < IT_G10) {
      const int iw = item - IT_W10;
      const int g0 = iw * 32768;
      for (int i2 = 0; i2 < 64; ++i2) deq1<256>(w1, w1s, W1b, g0 + i2 * 512 + tid);
      bump(&meta[M_W1 + (iw >> 4)], tid);
    } else if (item < IT_G20) {
      const int t = item - IT_G10, mt = t >> 3, nt = t & 7;
      const int slot0 = mt * 256;
      if (slot0 < meta[M_TOT]) {
        int e = 0;
#pragma unroll
        for (int i = 1; i < NEXP; ++i) e += (slot0 >= meta[8 + i]);
        if (tid == 0) {
          spin_ge(&meta[M_CAST], N_CAST);
          spin_ge(&meta[M_W1 + e], 16);
        }
        __syncthreads();
        gemm_body<2048, true>(xb, W1b + (size_t)e * 2048 * 2048, hbuf, out,
                              toklist, ewslot, lds, slot0, nt, tid);
        bump(&meta[M_DONE + mt], tid);
      }
    } else {
      const int t = item - IT_G20, mt = t >> 3, nt = t & 7;
      const int slot0 = mt * 256;
      if (slot0 < meta[M_TOT]) {
        int e = 0;
#pragma unroll
        for (int i = 1; i < NEXP; ++i) e += (slot0 >= meta[8 + i]);
        if (tid == 0) {
          spin_ge(&meta[M_ZERO], N_ZERO);
          spin_ge(&meta[M_W2], N_W2);
          spin_ge(&meta[M_DONE + mt], 8);
        }
        __syncthreads();
        gemm_body<1024, false>(hbuf, W2b + (size_t)e * 2048 * 1024, hbuf, out,
                               toklist, ewslot, lds, slot0, nt, tid);
      }
    }
  }
}

// ---------------- launch ----------------
extern "C" void kernel_launch(void* const* d_in, const int* in_sizes, int n_in,
                              void* d_out, int out_size, void* d_ws, size_t ws_size,
                              hipStream_t stream) {
  const float* x    = (const float*)d_in[0];
  const int*   w1   = (const int*)d_in[1];
  const float* w1s  = (const float*)d_in[2];
  const int*   w2   = (const int*)d_in[3];
  const float* w2s  = (const float*)d_in[4];
  const float* ew   = (const float*)d_in[5];
  const int*   eidx = (const int*)d_in[6];
  float* out = (float*)d_out;

  char* ws = (char*)d_ws;
  const size_t OFF_W1B  = 0;           // 67,108,864
  const size_t OFF_W2B  = 67108864;    // 33,554,432
  const size_t OFF_XB   = 100663296;   // 16,777,216
  const size_t OFF_H    = 117440512;   // 20,971,520
  const size_t OFF_META = 138412032;   // 10336 ints + 10240 floats = 82,304
  const size_t NEED     = 138494336;
  if (ws_size < NEED) return;

  u16* W1b  = (u16*)(ws + OFF_W1B);
  u16* W2b  = (u16*)(ws + OFF_W2B);
  u16* xb   = (u16*)(ws + OFF_XB);
  u16* hbuf = (u16*)(ws + OFF_H);
  int* meta = (int*)(ws + OFF_META);

  router_count<<<1, 256, 0, stream>>>(eidx, meta);
  init_k<<<SLOT_CAP / 256, 256, 0, stream>>>(meta);
  router_assign<<<T_TOK / 256, 256, 0, stream>>>(eidx, ew, meta);

  fused<<<256, 512, 0, stream>>>(x, w1, w1s, w2, w2s, xb, W1b, W2b, hbuf, out, meta);
}

// Round 8
// 325.853 us; speedup vs baseline: 1.4942x; 1.4942x over previous
//
#include <hip/hip_runtime.h>
#include <cstdint>
#include <cstddef>

typedef unsigned int u32;
typedef unsigned short u16;
typedef __bf16 bf16x8 __attribute__((ext_vector_type(8)));
typedef float f32x4 __attribute__((ext_vector_type(4)));
typedef u16 u16x8 __attribute__((ext_vector_type(8)));

static constexpr int T_TOK = 4096;
static constexpr int HID   = 2048;
static constexpr int INTER = 1024;
static constexpr int NEXP  = 8;
static constexpr int TOPK  = 2;
static constexpr int SLOT_CAP = 10240;   // 8192 real + per-expert 256-align pad
static constexpr int NT_M = 40;
static constexpr int N_G = 320;          // tiles per GEMM (40 mt x 8 nt)

// meta int indices
static constexpr int M_TOT   = 16;
static constexpr int M_CUR   = 17;   // 8 router cursors
static constexpr int M_Q     = 25;   // queue cursor
static constexpr int M_G1ALL = 26;   // all-G1-items-retired counter (gated mode)
static constexpr int M_DONE  = 40;   // 40 per-mt done counters
static constexpr int M_TOK   = 96;                    // toklist[SLOT_CAP]
static constexpr int M_SLOTOF = 96 + SLOT_CAP;        // slot_of[T*K]
static constexpr int META_INTS = 96 + SLOT_CAP + T_TOK * TOPK;  // 18528

__device__ __forceinline__ u16 f2bf(float f) {
  u32 u = __builtin_bit_cast(u32, f);
  u32 r = (u + 0x7fffu + ((u >> 16) & 1u)) >> 16;
  return (u16)r;
}
__device__ __forceinline__ float bf2f(u16 h) {
  return __builtin_bit_cast(float, (u32)h << 16);
}

__device__ __forceinline__ void spin_ge(int* p, int target) {
  while (__hip_atomic_load(p, __ATOMIC_ACQUIRE, __HIP_MEMORY_SCOPE_AGENT) < target)
    __builtin_amdgcn_s_sleep(8);
}
// all stores done -> __syncthreads() -> tid0: fence(L2 writeback) + release add.
// (R7-validated: cross-XCD consumer saw producer's hbuf correctly.)
__device__ __forceinline__ void bump(int* p, int tid) {
  __syncthreads();
  if (tid == 0) {
    __threadfence();
    __hip_atomic_fetch_add(p, 1, __ATOMIC_RELEASE, __HIP_MEMORY_SCOPE_AGENT);
  }
}

// ---------------- router ----------------
__global__ void router_count(const int* __restrict__ eidx, int* __restrict__ meta) {
  __shared__ int cnt[NEXP];
  const int tid = threadIdx.x;
  if (tid < NEXP) cnt[tid] = 0;
  __syncthreads();
  for (int i = tid; i < T_TOK * TOPK; i += 256) atomicAdd(&cnt[eidx[i]], 1);
  __syncthreads();
  if (tid == 0) {
    int off = 0;
    for (int e = 0; e < NEXP; ++e) {
      int c = cnt[e];
      meta[e] = c;
      meta[8 + e] = off;
      meta[M_CUR + e] = off;
      off += (c + 255) & ~255;      // 256-aligned regions (BM=256)
    }
    meta[M_TOT] = off;
  }
}

__global__ void init_k(int* __restrict__ meta) {
  const int i = blockIdx.x * 256 + threadIdx.x;
  if (i < SLOT_CAP) meta[M_TOK + i] = 0;   // pad rows gather token 0
  if (i >= 25 && i < 80) meta[i] = 0;      // Q, G1ALL, DONE[40]
}

__global__ void router_assign(const int* __restrict__ eidx, int* __restrict__ meta) {
  const int t = blockIdx.x * 256 + threadIdx.x;
  if (t >= T_TOK) return;
  int* cursors = meta + M_CUR;
  int* toklist = meta + M_TOK;
  int* slot_of = meta + M_SLOTOF;
  for (int k = 0; k < TOPK; ++k) {
    const int e = eidx[t * TOPK + k];
    const int pos = atomicAdd(&cursors[e], 1);
    toklist[pos] = t;
    slot_of[t * TOPK + k] = pos;
  }
}

// ---------------- dequant / cast ----------------
template <int CPR>
__global__ void dequant_k(const int* __restrict__ p, const float* __restrict__ s,
                          u16* __restrict__ w) {
  const int gid = blockIdx.x * 256 + threadIdx.x;
  const int row = gid / CPR;
  const int cid = gid % CPR;
  const int4 pk = *(const int4*)(p + (size_t)gid * 4);
  const float sc = s[(size_t)row * (CPR / 4) + (cid >> 2)];
  int v[4] = {pk.x, pk.y, pk.z, pk.w};
  u16x8 o;
#pragma unroll
  for (int b = 0; b < 4; ++b) {
    o[2 * b]     = f2bf((float)((v[b] & 15) - 8) * sc);
    o[2 * b + 1] = f2bf((float)(((v[b] >> 4) & 15) - 8) * sc);
  }
  *(u16x8*)(w + (size_t)gid * 8) = o;
}

__global__ void cast_x_k(const float* __restrict__ x, u16* __restrict__ xb) {
  const int i = (blockIdx.x * 256 + threadIdx.x) * 8;
  const float4 a = *(const float4*)(x + i);
  const float4 b = *(const float4*)(x + i + 4);
  u16x8 o;
  o[0] = f2bf(a.x); o[1] = f2bf(a.y); o[2] = f2bf(a.z); o[3] = f2bf(a.w);
  o[4] = f2bf(b.x); o[5] = f2bf(b.y); o[6] = f2bf(b.z); o[7] = f2bf(b.w);
  *(u16x8*)(xb + i) = o;
}

// ---------------- 256x256 GEMM tile body (R5 2-phase, conflict-free swizzle) ----------------
// C[slot, n] = sum_k A[row(slot), k] * B[n, k]  (B K-major). BM=BN=256, BK=64,
// 8 waves (2M x 4N), wave tile 128x64, dbuf LDS 2x64KB. Swizzle o^=((o>>7)&3)<<4
// (R7-verified: SQ_LDS_BANK_CONFLICT = 0). G1M: gather A rows + silu(gate)*up epilogue.
template <int KT, bool G1M>
__device__ void gemm_body(const u16* __restrict__ A, const u16* __restrict__ Be,
                          u16* __restrict__ Cout, const int* __restrict__ toklist,
                          u16* lds, int slot0, int nt, int tid) {
  static constexpr int NT = KT / 64;
  static constexpr int OSTR = G1M ? INTER : HID;
  char* ldsB = (char*)lds;

  const u16* asrc[4];
  const u16* bsrc[4];
#pragma unroll
  for (int j = 0; j < 4; ++j) {
    const int L = j * 8192 + tid * 16;
    const int S = L >> 10;
    int o = L & 1023;
    o ^= ((o >> 7) & 3) << 4;
    const int r = (S >> 1) * 16 + (o >> 6);
    const int cb = (S & 1) * 64 + (o & 63);
    const int arow = G1M ? toklist[slot0 + r] : (slot0 + r);
    asrc[j] = A + (size_t)arow * KT + (cb >> 1);
    int brow;
    if (G1M) {
      const int g = r >> 6, j6 = r & 63;
      brow = nt * 128 + g * 32 + (j6 & 31) + ((j6 >> 5) << 10);  // gate | up+1024
    } else {
      brow = nt * 256 + r;
    }
    bsrc[j] = Be + (size_t)brow * KT + (cb >> 1);
  }

#define STAGE(kt_, c_)                                                                \
  do {                                                                                \
    char* dA_ = ldsB + (c_) * 65536;                                                  \
    char* dB_ = dA_ + 32768;                                                          \
    _Pragma("unroll") for (int j = 0; j < 4; ++j)                                     \
        __builtin_amdgcn_global_load_lds(                                             \
            (const __attribute__((address_space(1))) void*)(asrc[j] + (kt_) * 64),    \
            (__attribute__((address_space(3))) void*)(dA_ + j * 8192 + tid * 16),     \
            16, 0, 0);                                                                \
    _Pragma("unroll") for (int j = 0; j < 4; ++j)                                     \
        __builtin_amdgcn_global_load_lds(                                             \
            (const __attribute__((address_space(1))) void*)(bsrc[j] + (kt_) * 64),    \
            (__attribute__((address_space(3))) void*)(dB_ + j * 8192 + tid * 16),     \
            16, 0, 0);                                                                \
  } while (0)

  const int lane = tid & 63;
  const int wid = tid >> 6;
  const int wm = (wid >> 2) * 128;
  const int wn = (wid & 3) * 64;
  const int fr = lane & 15;
  const int qq = lane >> 4;
  const int swz = (qq * 16) ^ (((fr >> 1) & 3) << 4);

  const int abase = (wm >> 4) * 2048 + fr * 64 + swz;
  const int bbase = 32768 + (wn >> 4) * 2048 + fr * 64 + swz;

  f32x4 acc[8][4];
#pragma unroll
  for (int m = 0; m < 8; ++m)
#pragma unroll
    for (int n = 0; n < 4; ++n) acc[m][n] = (f32x4)0.0f;

#define COMPUTE(c_)                                                                   \
  do {                                                                                \
    const char* bb_ = ldsB + (c_) * 65536;                                            \
    bf16x8 bfr_[4][2];                                                                \
    _Pragma("unroll") for (int nf = 0; nf < 4; ++nf)                                  \
        _Pragma("unroll") for (int ks = 0; ks < 2; ++ks)                              \
            bfr_[nf][ks] = *(const bf16x8*)(bb_ + bbase + nf * 2048 + ks * 1024);     \
    _Pragma("unroll") for (int mh = 0; mh < 2; ++mh) {                                \
      bf16x8 af_[4][2];                                                               \
      _Pragma("unroll") for (int mf = 0; mf < 4; ++mf)                                \
          _Pragma("unroll") for (int ks = 0; ks < 2; ++ks)                            \
              af_[mf][ks] = *(const bf16x8*)(bb_ + abase + mh * 8192 + mf * 2048 +    \
                                             ks * 1024);                              \
      __builtin_amdgcn_s_setprio(1);                                                  \
      _Pragma("unroll") for (int mf = 0; mf < 4; ++mf)                                \
          _Pragma("unroll") for (int nf = 0; nf < 4; ++nf)                            \
              _Pragma("unroll") for (int ks = 0; ks < 2; ++ks)                        \
                  acc[mh * 4 + mf][nf] = __builtin_amdgcn_mfma_f32_16x16x32_bf16(     \
                      af_[mf][ks], bfr_[nf][ks], acc[mh * 4 + mf][nf], 0, 0, 0);      \
      __builtin_amdgcn_s_setprio(0);                                                  \
    }                                                                                 \
  } while (0)

  STAGE(0, 0);
#pragma unroll 1
  for (int kt = 0; kt < NT; kt += 2) {
    asm volatile("s_waitcnt vmcnt(0)" ::: "memory");
    __builtin_amdgcn_s_barrier();
    __builtin_amdgcn_sched_barrier(0);
    if (kt + 1 < NT) STAGE(kt + 1, 1);
    COMPUTE(0);
    asm volatile("s_waitcnt vmcnt(0)" ::: "memory");
    __builtin_amdgcn_s_barrier();
    __builtin_amdgcn_sched_barrier(0);
    if (kt + 2 < NT) STAGE(kt + 2, 0);
    COMPUTE(1);
  }
#undef STAGE
#undef COMPUTE

  // epilogue: C/D layout col=lane&15, row=(lane>>4)*4+j  [m89-verified]
  if (G1M) {
    const int g = wid & 3;
#pragma unroll
    for (int mi = 0; mi < 8; ++mi)
#pragma unroll
      for (int n = 0; n < 2; ++n)
#pragma unroll
        for (int jj = 0; jj < 4; ++jj) {
          const float gv = acc[mi][n][jj];
          const float uv = acc[mi][n + 2][jj];
          const float hv = gv / (1.0f + __expf(-gv)) * uv;
          const int row = slot0 + wm + mi * 16 + qq * 4 + jj;
          Cout[(size_t)row * OSTR + nt * 128 + g * 32 + n * 16 + fr] = f2bf(hv);
        }
  } else {
#pragma unroll
    for (int mi = 0; mi < 8; ++mi)
#pragma unroll
      for (int n = 0; n < 4; ++n)
#pragma unroll
        for (int jj = 0; jj < 4; ++jj) {
          const int row = slot0 + wm + mi * 16 + qq * 4 + jj;
          const int col = nt * 256 + wn + n * 16 + fr;
          Cout[(size_t)row * OSTR + col] = f2bf(acc[mi][n][jj]);
        }
  }
}

// ---------------- persistent GEMM (256 workers, 640-tile queue) ----------------
// Queue: [G1 tiles 320, mt-major][G2 tiles 320, mt-major]. Pops are in cursor
// order; every dependency is an earlier item -> no deadlock. G2 mt spins on
// done[mt]==8 (ungated) or all-G1 (gated fallback when yp aliases W1b).
__global__ __launch_bounds__(512, 2) void gemm_pers(
    const u16* __restrict__ xb, const u16* __restrict__ W1b,
    const u16* __restrict__ W2b, u16* __restrict__ hbuf, u16* __restrict__ yp,
    int* __restrict__ meta, int gated) {
  __shared__ u16 lds[2 * 32768];
  __shared__ int sh_item;
  const int tid = threadIdx.x;
  const int* toklist = meta + M_TOK;

  for (;;) {
    __syncthreads();
    if (tid == 0) sh_item = atomicAdd(&meta[M_Q], 1);
    __syncthreads();
    const int item = sh_item;
    if (item >= 2 * N_G) return;

    if (item < N_G) {
      const int mt = item >> 3, nt = item & 7, slot0 = mt * 256;
      if (slot0 < meta[M_TOT]) {
        int e = 0;
#pragma unroll
        for (int i = 1; i < NEXP; ++i) e += (slot0 >= meta[8 + i]);
        gemm_body<2048, true>(xb, W1b + (size_t)e * 2048 * 2048, hbuf, toklist,
                              lds, slot0, nt, tid);
        bump(&meta[M_DONE + mt], tid);
      }
      bump(&meta[M_G1ALL], tid);
    } else {
      const int t = item - N_G, mt = t >> 3, nt = t & 7, slot0 = mt * 256;
      if (slot0 < meta[M_TOT]) {
        int e = 0;
#pragma unroll
        for (int i = 1; i < NEXP; ++i) e += (slot0 >= meta[8 + i]);
        if (tid == 0) {
          if (gated) spin_ge(&meta[M_G1ALL], N_G);
          else spin_ge(&meta[M_DONE + mt], 8);
        }
        __syncthreads();
        gemm_body<1024, false>(hbuf, W2b + (size_t)e * 2048 * 1024, yp, toklist,
                               lds, slot0, nt, tid);
      }
    }
  }
}

// ---------------- combine ----------------
__global__ void combine_k(const u16* __restrict__ yp, const float* __restrict__ ew,
                          const int* __restrict__ meta, float* __restrict__ out) {
  const int idx = blockIdx.x * 256 + threadIdx.x;
  const int t = idx >> 8;
  const int pos = (idx & 255) * 8;
  const int* slot_of = meta + M_SLOTOF;
  const int s0 = slot_of[t * 2];
  const int s1 = slot_of[t * 2 + 1];
  const float w0 = ew[t * 2];
  const float w1 = ew[t * 2 + 1];
  const u16x8 v0 = *(const u16x8*)(yp + (size_t)s0 * 2048 + pos);
  const u16x8 v1 = *(const u16x8*)(yp + (size_t)s1 * 2048 + pos);
  float* dst = out + (size_t)t * 2048 + pos;
  float4 o0, o1;
  o0.x = w0 * bf2f(v0[0]) + w1 * bf2f(v1[0]);
  o0.y = w0 * bf2f(v0[1]) + w1 * bf2f(v1[1]);
  o0.z = w0 * bf2f(v0[2]) + w1 * bf2f(v1[2]);
  o0.w = w0 * bf2f(v0[3]) + w1 * bf2f(v1[3]);
  o1.x = w0 * bf2f(v0[4]) + w1 * bf2f(v1[4]);
  o1.y = w0 * bf2f(v0[5]) + w1 * bf2f(v1[5]);
  o1.z = w0 * bf2f(v0[6]) + w1 * bf2f(v1[6]);
  o1.w = w0 * bf2f(v0[7]) + w1 * bf2f(v1[7]);
  *(float4*)dst = o0;
  *(float4*)(dst + 4) = o1;
}

// ---------------- launch ----------------
extern "C" void kernel_launch(void* const* d_in, const int* in_sizes, int n_in,
                              void* d_out, int out_size, void* d_ws, size_t ws_size,
                              hipStream_t stream) {
  const float* x    = (const float*)d_in[0];
  const int*   w1   = (const int*)d_in[1];
  const float* w1s  = (const float*)d_in[2];
  const int*   w2   = (const int*)d_in[3];
  const float* w2s  = (const float*)d_in[4];
  const float* ew   = (const float*)d_in[5];
  const int*   eidx = (const int*)d_in[6];
  float* out = (float*)d_out;

  char* ws = (char*)d_ws;
  const size_t OFF_W1B  = 0;           // 67,108,864
  const size_t OFF_W2B  = 67108864;    // 33,554,432
  const size_t OFF_XB   = 100663296;   // 16,777,216
  const size_t OFF_H    = 117440512;   // 20,971,520
  const size_t OFF_META = 138412032;   // 18,528 ints -> pad to 76,800
  const size_t OFF_YP_A = 138488832;   // 10240*2048*2 = 41,943,040 (layout A only)
  const size_t NEED_B   = 138488832;
  const size_t NEED_A   = 180431872;
  if (ws_size < NEED_B) return;
  // gated fallback: yp aliases W1b; G2 waits for ALL G1 (no G1/G2 overlap).
  const int gated = (ws_size < NEED_A) ? 1 : 0;

  u16* W1b  = (u16*)(ws + OFF_W1B);
  u16* W2b  = (u16*)(ws + OFF_W2B);
  u16* xb   = (u16*)(ws + OFF_XB);
  u16* hbuf = (u16*)(ws + OFF_H);
  int* meta = (int*)(ws + OFF_META);
  u16* yp   = gated ? (u16*)(ws + OFF_W1B) : (u16*)(ws + OFF_YP_A);

  router_count<<<1, 256, 0, stream>>>(eidx, meta);
  init_k<<<SLOT_CAP / 256, 256, 0, stream>>>(meta);
  router_assign<<<T_TOK / 256, 256, 0, stream>>>(eidx, meta);

  cast_x_k<<<(T_TOK * HID) / (256 * 8), 256, 0, stream>>>(x, xb);
  dequant_k<256><<<16384, 256, 0, stream>>>(w1, w1s, W1b);
  dequant_k<128><<<8192, 256, 0, stream>>>(w2, w2s, W2b);

  gemm_pers<<<256, 512, 0, stream>>>(xb, W1b, W2b, hbuf, yp, meta, gated);

  combine_k<<<(T_TOK * HID) / (256 * 8), 256, 0, stream>>>(yp, ew, meta, out);
}